// Round 1
// baseline (2338.339 us; speedup 1.0000x reference)
//
#include <hip/hip_runtime.h>
#include <hip/hip_bf16.h>
#include <stdint.h>

// Problem: out[n,o] = sum_i x[n,i] * w_dq[o,i] + bias[o]
//   x: [8192, 4096] f32, weight: [16384, 4096] f32, bias: [16384] f32
//   w_dq = clip(round(w/scale), -8, 7) * scale, scale = max(max|w|/7, 1e-8)
#define M_DIM 8192
#define K_DIM 4096
#define N_DIM 16384

#define BM 128
#define BN 128
#define BK 32

typedef __attribute__((ext_vector_type(8))) short    short8;   // 8 bf16 (4 VGPRs) MFMA A/B frag
typedef __attribute__((ext_vector_type(4))) float    f32x4;    // MFMA C/D frag
typedef __attribute__((ext_vector_type(8))) unsigned short ushort8;

// f32 -> bf16, round-to-nearest-even (finite inputs only)
__device__ inline unsigned short f2bf(float f) {
    unsigned u = __float_as_uint(f);
    u = (u + 0x7fffu + ((u >> 16) & 1u)) >> 16;
    return (unsigned short)u;
}

// ---------------- kernel 1: max|w| reduction ----------------
__global__ void absmax_kernel(const float* __restrict__ w, unsigned* __restrict__ out, int n4) {
    int tid = blockIdx.x * blockDim.x + threadIdx.x;
    int stride = gridDim.x * blockDim.x;
    float m = 0.0f;
    for (int i = tid; i < n4; i += stride) {
        float4 v = ((const float4*)w)[i];
        m = fmaxf(m, fmaxf(fmaxf(fabsf(v.x), fabsf(v.y)), fmaxf(fabsf(v.z), fabsf(v.w))));
    }
    #pragma unroll
    for (int off = 32; off > 0; off >>= 1)
        m = fmaxf(m, __shfl_down(m, off, 64));
    __shared__ float smax[4];
    int lane = threadIdx.x & 63, wv = threadIdx.x >> 6;
    if (lane == 0) smax[wv] = m;
    __syncthreads();
    if (threadIdx.x == 0) {
        float b = fmaxf(fmaxf(smax[0], smax[1]), fmaxf(smax[2], smax[3]));
        atomicMax(out, __float_as_uint(b));   // all values >= 0: IEEE bits order as uints
    }
}

// ---------------- kernel 2: quantize+dequant weight -> bf16 ----------------
__global__ void quant_w_kernel(const float* __restrict__ w, const unsigned* __restrict__ maxbits,
                               unsigned short* __restrict__ wq, int n8) {
    float scale = fmaxf(__uint_as_float(*maxbits) / 7.0f, 1e-8f);
    int tid = blockIdx.x * blockDim.x + threadIdx.x;
    int stride = gridDim.x * blockDim.x;
    for (int i = tid; i < n8; i += stride) {
        float4 a = ((const float4*)w)[2 * i];
        float4 b = ((const float4*)w)[2 * i + 1];
        float v[8] = {a.x, a.y, a.z, a.w, b.x, b.y, b.z, b.w};
        ushort8 o;
        #pragma unroll
        for (int j = 0; j < 8; j++) {
            // true division + rintf => bit-exact match with numpy round-half-even
            float q = rintf(v[j] / scale);
            q = fminf(fmaxf(q, -8.0f), 7.0f);
            o[j] = f2bf(q * scale);
        }
        ((ushort8*)wq)[i] = o;
    }
}

// ---------------- kernel 3: x f32 -> bf16 ----------------
__global__ void cvt_x_kernel(const float* __restrict__ x, unsigned short* __restrict__ xb, int n8) {
    int tid = blockIdx.x * blockDim.x + threadIdx.x;
    int stride = gridDim.x * blockDim.x;
    for (int i = tid; i < n8; i += stride) {
        float4 a = ((const float4*)x)[2 * i];
        float4 b = ((const float4*)x)[2 * i + 1];
        ushort8 o;
        o[0] = f2bf(a.x); o[1] = f2bf(a.y); o[2] = f2bf(a.z); o[3] = f2bf(a.w);
        o[4] = f2bf(b.x); o[5] = f2bf(b.y); o[6] = f2bf(b.z); o[7] = f2bf(b.w);
        ((ushort8*)xb)[i] = o;
    }
}

// ---------------- kernel 4: bf16 GEMM (B^T input) + bias, f32 out ----------------
// A: [M,K] bf16 row-major (x), B: [N,K] bf16 row-major (w_dq), C: [M,N] f32.
// m97-ladder structure: 128x128 tile, BK=32, 4 waves, 4x4 16x16x32 MFMAs/wave,
// global_load_lds width=16 staging (contiguous LDS, no padding -- required).
__global__ __launch_bounds__(256)
void gemm_bt_bias(const unsigned short* __restrict__ A,
                  const unsigned short* __restrict__ B,
                  const float* __restrict__ bias,
                  float* __restrict__ C) {
    __shared__ __align__(16) unsigned short As[BM * BK];  // 8 KB
    __shared__ __align__(16) unsigned short Bs[BN * BK];  // 8 KB

    const int tid  = threadIdx.x;
    const int lane = tid & 63;
    const int wv   = tid >> 6;          // wave 0..3
    const int wr   = wv >> 1;           // wave row (0..1) -> 64 rows
    const int wc   = wv & 1;            // wave col (0..1) -> 64 cols
    const int l15  = lane & 15;
    const int quad = lane >> 4;

    const long arow0 = (long)blockIdx.y * BM;
    const long brow0 = (long)blockIdx.x * BN;

    // staging: chunk = r*256 + tid (16B each); row = chunk>>2, kchunk = chunk&3
    const unsigned short* aptr0 = A + (arow0 + (tid >> 2)) * K_DIM + (tid & 3) * 8;
    const unsigned short* aptr1 = A + (arow0 + 64 + (tid >> 2)) * K_DIM + (tid & 3) * 8;
    const unsigned short* bptr0 = B + (brow0 + (tid >> 2)) * K_DIM + (tid & 3) * 8;
    const unsigned short* bptr1 = B + (brow0 + 64 + (tid >> 2)) * K_DIM + (tid & 3) * 8;
    unsigned short* lA0 = As + tid * 8;
    unsigned short* lA1 = As + 2048 + tid * 8;
    unsigned short* lB0 = Bs + tid * 8;
    unsigned short* lB1 = Bs + 2048 + tid * 8;

    f32x4 acc[4][4];
    #pragma unroll
    for (int mi = 0; mi < 4; mi++)
        #pragma unroll
        for (int ni = 0; ni < 4; ni++)
            acc[mi][ni] = 0.0f;

    for (int k0 = 0; k0 < K_DIM; k0 += BK) {
        __builtin_amdgcn_global_load_lds(
            (const __attribute__((address_space(1))) void*)(aptr0 + k0),
            (__attribute__((address_space(3))) void*)lA0, 16, 0, 0);
        __builtin_amdgcn_global_load_lds(
            (const __attribute__((address_space(1))) void*)(aptr1 + k0),
            (__attribute__((address_space(3))) void*)lA1, 16, 0, 0);
        __builtin_amdgcn_global_load_lds(
            (const __attribute__((address_space(1))) void*)(bptr0 + k0),
            (__attribute__((address_space(3))) void*)lB0, 16, 0, 0);
        __builtin_amdgcn_global_load_lds(
            (const __attribute__((address_space(1))) void*)(bptr1 + k0),
            (__attribute__((address_space(3))) void*)lB1, 16, 0, 0);
        __syncthreads();  // compiler emits vmcnt(0) drain before s_barrier

        short8 af[4], bfr[4];
        #pragma unroll
        for (int mi = 0; mi < 4; mi++)
            af[mi] = *(const short8*)(As + (wr * 64 + mi * 16 + l15) * BK + quad * 8);
        #pragma unroll
        for (int ni = 0; ni < 4; ni++)
            bfr[ni] = *(const short8*)(Bs + (wc * 64 + ni * 16 + l15) * BK + quad * 8);

        #pragma unroll
        for (int mi = 0; mi < 4; mi++)
            #pragma unroll
            for (int ni = 0; ni < 4; ni++)
                acc[mi][ni] = __builtin_amdgcn_mfma_f32_16x16x32_bf16(
                    af[mi], bfr[ni], acc[mi][ni], 0, 0, 0);

        __syncthreads();  // protect LDS before next stage
    }

    // epilogue: C/D layout col=lane&15, row=quad*4+reg
    const long crow0 = arow0 + wr * 64;
    const long ccol0 = brow0 + wc * 64;
    #pragma unroll
    for (int ni = 0; ni < 4; ni++) {
        const long col = ccol0 + ni * 16 + l15;
        const float bv = bias[col];
        #pragma unroll
        for (int mi = 0; mi < 4; mi++) {
            #pragma unroll
            for (int v = 0; v < 4; v++) {
                const long row = crow0 + mi * 16 + quad * 4 + v;
                C[row * N_DIM + col] = acc[mi][ni][v] + bv;
            }
        }
    }
}

extern "C" void kernel_launch(void* const* d_in, const int* in_sizes, int n_in,
                              void* d_out, int out_size, void* d_ws, size_t ws_size,
                              hipStream_t stream) {
    const float* x    = (const float*)d_in[0];   // [8192, 4096]
    const float* w    = (const float*)d_in[1];   // [16384, 4096]
    const float* bias = (const float*)d_in[2];   // [16384]
    float* out        = (float*)d_out;           // [8192, 16384]

    // workspace layout: [0,4) max|w| bits; +256: x_bf16 (64 MiB); then w_bf16 (128 MiB)
    unsigned* maxbits  = (unsigned*)d_ws;
    unsigned short* xb = (unsigned short*)((char*)d_ws + 256);
    unsigned short* wb = (unsigned short*)((char*)d_ws + 256 + (size_t)M_DIM * K_DIM * 2);

    hipMemsetAsync(d_ws, 0, 4, stream);  // zero the atomicMax slot (ws is poisoned 0xAA)

    absmax_kernel<<<4096, 256, 0, stream>>>(w, maxbits, (N_DIM * K_DIM) / 4);
    quant_w_kernel<<<4096, 256, 0, stream>>>(w, maxbits, wb, (N_DIM * K_DIM) / 8);
    cvt_x_kernel<<<4096, 256, 0, stream>>>(x, xb, (M_DIM * K_DIM) / 8);

    dim3 grid(N_DIM / BN, M_DIM / BM);   // (128, 64) = 8192 blocks
    gemm_bt_bias<<<grid, 256, 0, stream>>>(xb, wb, bias, out);
}